// Round 1
// baseline (447.811 us; speedup 1.0000x reference)
//
#include <hip/hip_runtime.h>
#include <hip/hip_bf16.h>

#define NN 50000
#define EE 200000
#define HH 8
#define CC 256
#define IND 256
#define HC 2048
#define NEG 0.2f
#define EPSV 1e-16f

typedef __attribute__((ext_vector_type(8))) short short8;
typedef __attribute__((ext_vector_type(4))) float f32x4;

__device__ __forceinline__ float b2f(unsigned short u) {
  return __uint_as_float(((unsigned)u) << 16);
}
__device__ __forceinline__ unsigned short f2b(float f) {
  unsigned u = __float_as_uint(f);
  unsigned r = (u + 0x7FFFu + ((u >> 16) & 1u)) >> 16;
  return (unsigned short)r;
}

// ---------------- convert x, W to bf16 ----------------
__global__ __launch_bounds__(256) void k_convert(const float* __restrict__ x,
                                                 const float* __restrict__ W,
                                                 unsigned short* __restrict__ xb,
                                                 unsigned short* __restrict__ wb) {
  int i = blockIdx.x * 256 + threadIdx.x;
  const int NX4 = NN * IND / 4;
  const int NW4 = IND * HC / 4;
  if (i < NX4) {
    float4 v = ((const float4*)x)[i];
    ushort4 o = make_ushort4(f2b(v.x), f2b(v.y), f2b(v.z), f2b(v.w));
    ((ushort4*)xb)[i] = o;
  } else if (i < NX4 + NW4) {
    int j = i - NX4;
    float4 v = ((const float4*)W)[j];
    ushort4 o = make_ushort4(f2b(v.x), f2b(v.y), f2b(v.z), f2b(v.w));
    ((ushort4*)wb)[j] = o;
  }
}

// ---------------- GEMM: h = x @ W  (bf16 MFMA, 128x128 tile) ----------------
__global__ __launch_bounds__(256) void k_gemm(const unsigned short* __restrict__ xb,
                                              const unsigned short* __restrict__ wb,
                                              unsigned short* __restrict__ hb) {
  __shared__ short As[128][40];   // [row][k], +8 pad
  __shared__ short Bs[128][40];   // transposed: [col][k], +8 pad
  const int n0 = blockIdx.x * 128;
  const int m0 = blockIdx.y * 128;
  const int t = threadIdx.x;
  const int lane = t & 63;
  const int w = t >> 6;
  const int wr = w >> 1, wc = w & 1;
  const int l16 = lane & 15;
  const int lk8 = (lane >> 4) * 8;

  f32x4 acc[4][4] = {};

  for (int ks = 0; ks < 8; ++ks) {
    const int k0 = ks * 32;
#pragma unroll
    for (int r = 0; r < 2; ++r) {
      int id = t + r * 256;          // 0..511
      int row = id >> 2;
      int c0 = (id & 3) * 8;
      int grow = m0 + row;
      short8 v{};
      if (grow < NN) v = *(const short8*)(xb + (size_t)grow * IND + k0 + c0);
      *(short8*)(&As[row][c0]) = v;
    }
#pragma unroll
    for (int r = 0; r < 2; ++r) {
      int id = t + r * 256;
      int k = id >> 4;               // 0..31
      int c0 = (id & 15) * 8;
      short8 v = *(const short8*)(wb + (size_t)(k0 + k) * HC + n0 + c0);
#pragma unroll
      for (int j = 0; j < 8; ++j) Bs[c0 + j][k] = v[j];
    }
    __syncthreads();
    short8 af[4], bf[4];
#pragma unroll
    for (int m = 0; m < 4; ++m) af[m] = *(const short8*)(&As[wr * 64 + m * 16 + l16][lk8]);
#pragma unroll
    for (int n = 0; n < 4; ++n) bf[n] = *(const short8*)(&Bs[wc * 64 + n * 16 + l16][lk8]);
#pragma unroll
    for (int m = 0; m < 4; ++m)
#pragma unroll
      for (int n = 0; n < 4; ++n)
        acc[m][n] = __builtin_amdgcn_mfma_f32_16x16x32_bf16(af[m], bf[n], acc[m][n], 0, 0, 0);
    __syncthreads();
  }

  const int r0 = (lane >> 4) * 4;
#pragma unroll
  for (int m = 0; m < 4; ++m) {
#pragma unroll
    for (int r = 0; r < 4; ++r) {
      int grow = m0 + wr * 64 + m * 16 + r0 + r;
      if (grow >= NN) continue;
#pragma unroll
      for (int n = 0; n < 4; ++n) {
        int gcol = n0 + wc * 64 + n * 16 + l16;
        hb[(size_t)grow * HC + gcol] = f2b(acc[m][n][r]);
      }
    }
  }
}

// ---------------- per-node attention logits ----------------
__global__ __launch_bounds__(256) void k_alogits(const unsigned short* __restrict__ hb,
                                                 const float* __restrict__ att_s,
                                                 const float* __restrict__ att_d,
                                                 float* __restrict__ a_src,
                                                 float* __restrict__ a_dst) {
  int n = blockIdx.x;
  int t = threadIdx.x;
  int head = t >> 5;
  int off = (t & 31) * 8;
  short8 hv = *(const short8*)(hb + (size_t)n * HC + head * 256 + off);
  float ps = 0.f, pd = 0.f;
#pragma unroll
  for (int j = 0; j < 8; ++j) {
    float hf = b2f((unsigned short)hv[j]);
    ps += hf * att_s[head * 256 + off + j];
    pd += hf * att_d[head * 256 + off + j];
  }
#pragma unroll
  for (int o = 16; o >= 1; o >>= 1) {
    ps += __shfl_down(ps, o, 32);
    pd += __shfl_down(pd, o, 32);
  }
  if ((t & 31) == 0) {
    a_src[n * HH + head] = ps;
    a_dst[n * HH + head] = pd;
  }
}

// ---------------- CSR build ----------------
__global__ void k_hist(const int* __restrict__ dstn, int* __restrict__ deg) {
  int e = blockIdx.x * 256 + threadIdx.x;
  if (e < EE) atomicAdd(&deg[dstn[e]], 1);
}

__global__ __launch_bounds__(1024) void k_scanA(const int* __restrict__ deg,
                                                int* __restrict__ incl, int* __restrict__ bsum) {
  __shared__ int s[1024];
  int tid = threadIdx.x;
  int i = blockIdx.x * 1024 + tid;
  s[tid] = (i < NN) ? deg[i] : 0;
  __syncthreads();
  for (int o = 1; o < 1024; o <<= 1) {
    int add = (tid >= o) ? s[tid - o] : 0;
    __syncthreads();
    s[tid] += add;
    __syncthreads();
  }
  if (i < NN) incl[i] = s[tid];
  if (tid == 1023) bsum[blockIdx.x] = s[1023];
}

__global__ void k_scanB(int* bsum, int nb) {
  if (threadIdx.x == 0 && blockIdx.x == 0) {
    int run = 0;
    for (int b = 0; b < nb; ++b) { int v = bsum[b]; bsum[b] = run; run += v; }
  }
}

__global__ __launch_bounds__(1024) void k_scanC(const int* __restrict__ deg, const int* __restrict__ incl,
                                                const int* __restrict__ bsum, int* __restrict__ row_start,
                                                int* __restrict__ cursor) {
  int i = blockIdx.x * 1024 + threadIdx.x;
  if (i < NN) {
    int ex = bsum[i >> 10] + incl[i] - deg[i];
    row_start[i] = ex;
    cursor[i] = ex;
  }
  if (i == 0) row_start[NN] = EE;
}

__global__ void k_scatter(const int* __restrict__ srcn, const int* __restrict__ dstn,
                          int* __restrict__ cursor, int* __restrict__ csr_src) {
  int e = blockIdx.x * 256 + threadIdx.x;
  if (e < EE) {
    int d = dstn[e];
    int p = atomicAdd(&cursor[d], 1);
    csr_src[p] = srcn[e];
  }
}

// ---------------- fused segment softmax + aggregation ----------------
__global__ __launch_bounds__(256) void k_agg(const unsigned short* __restrict__ hb,
                                             const float* __restrict__ a_src,
                                             const float* __restrict__ a_dst,
                                             const int* __restrict__ row_start,
                                             const int* __restrict__ csr_src,
                                             const float* __restrict__ bias,
                                             float* __restrict__ out) {
  __shared__ float m_s[8], d_s[8];
  __shared__ float alpha_s[8][8];   // [edge_in_chunk][head]
  __shared__ int src_s[8];
  __shared__ float redf[8][256];
  int n = blockIdx.x;
  int t = threadIdx.x;
  int start = row_start[n];
  int D = row_start[n + 1] - start;
  if (D == 0) {
    out[(size_t)n * CC + t] = bias[t];
    return;
  }
  // phase A: online softmax stats (wave 0; lane = e8*8 + h)
  if (t < 64) {
    int h = t & 7, e8 = t >> 3;
    float adst = a_dst[n * HH + h];
    float m = -INFINITY, ss = 0.f;
    for (int base = 0; base < D; base += 8) {
      int e = base + e8;
      float lg = -INFINITY;
      if (e < D) {
        int s = csr_src[start + e];
        float xv = a_src[s * HH + h] + adst;
        lg = (xv > 0.f) ? xv : NEG * xv;
      }
      if (lg > m) { ss *= __expf(m - lg); m = lg; }
      if (e < D) ss += __expf(lg - m);
    }
#pragma unroll
    for (int mask = 8; mask < 64; mask <<= 1) {
      float mo = __shfl_xor(m, mask);
      float so = __shfl_xor(ss, mask);
      float nm = fmaxf(m, mo);
      float s1 = (m == -INFINITY) ? 0.f : ss * __expf(m - nm);
      float s2 = (mo == -INFINITY) ? 0.f : so * __expf(mo - nm);
      m = nm; ss = s1 + s2;
    }
    if (e8 == 0) { m_s[h] = m; d_s[h] = ss; }
  }
  __syncthreads();

  // phase B: aggregate; thread covers head hA, channels c8..c8+7
  const int hA = t >> 5;
  const int c8 = (t & 31) * 8;
  float acc[8] = {0.f, 0.f, 0.f, 0.f, 0.f, 0.f, 0.f, 0.f};
  for (int base = 0; base < D; base += 8) {
    int nch = min(8, D - base);
    if (t < 64) {
      int h = t & 7, e8 = t >> 3;
      if (e8 < nch) {
        int s = csr_src[start + base + e8];
        if (h == 0) src_s[e8] = s;
        float xv = a_src[s * HH + h] + a_dst[n * HH + h];
        float lg = (xv > 0.f) ? xv : NEG * xv;
        alpha_s[e8][h] = __expf(lg - m_s[h]) / (d_s[h] + EPSV);
      }
    }
    __syncthreads();
    for (int e = 0; e < nch; ++e) {
      const unsigned short* hp = hb + (size_t)src_s[e] * HC + hA * 256 + c8;
      short8 v = *(const short8*)hp;
      float a = alpha_s[e][hA];
#pragma unroll
      for (int j = 0; j < 8; ++j) acc[j] += a * b2f((unsigned short)v[j]);
    }
    __syncthreads();
  }
  // head-mean reduction
#pragma unroll
  for (int j = 0; j < 8; ++j) redf[hA][c8 + j] = acc[j];
  __syncthreads();
  float s = 0.f;
#pragma unroll
  for (int h = 0; h < 8; ++h) s += redf[h][t];
  out[(size_t)n * CC + t] = s * 0.125f + bias[t];
}

// ---------------- launch ----------------
extern "C" void kernel_launch(void* const* d_in, const int* in_sizes, int n_in,
                              void* d_out, int out_size, void* d_ws, size_t ws_size,
                              hipStream_t stream) {
  (void)in_sizes; (void)n_in; (void)out_size; (void)ws_size;
  const float* x = (const float*)d_in[0];
  const int* ei = (const int*)d_in[1];
  const float* W = (const float*)d_in[2];
  const float* att_s = (const float*)d_in[3];
  const float* att_d = (const float*)d_in[4];
  const float* bias = (const float*)d_in[5];
  float* out = (float*)d_out;
  const int* srcp = ei;
  const int* dstp = ei + EE;

  char* ws = (char*)d_ws;
  size_t off = 0;
  auto alloc = [&](size_t bytes) {
    void* p = ws + off;
    off = (off + bytes + 255) & ~(size_t)255;
    return p;
  };
  unsigned short* hb = (unsigned short*)alloc((size_t)NN * HC * 2);
  unsigned short* xb = (unsigned short*)alloc((size_t)NN * IND * 2);
  unsigned short* wb = (unsigned short*)alloc((size_t)IND * HC * 2);
  float* a_src = (float*)alloc((size_t)NN * HH * 4);
  float* a_dst = (float*)alloc((size_t)NN * HH * 4);
  int* deg = (int*)alloc((size_t)NN * 4);
  int* incl = (int*)alloc((size_t)NN * 4);
  int* row_start = (int*)alloc((size_t)(NN + 1) * 4);
  int* cursor = (int*)alloc((size_t)NN * 4);
  int* csr_src = (int*)alloc((size_t)EE * 4);
  int* bsum = (int*)alloc(256);

  hipMemsetAsync(deg, 0, (size_t)NN * 4, stream);

  int conv_blocks = (NN * IND / 4 + IND * HC / 4 + 255) / 256;
  k_convert<<<conv_blocks, 256, 0, stream>>>(x, W, xb, wb);
  k_gemm<<<dim3(16, 391), 256, 0, stream>>>(xb, wb, hb);
  k_alogits<<<NN, 256, 0, stream>>>(hb, att_s, att_d, a_src, a_dst);
  k_hist<<<(EE + 255) / 256, 256, 0, stream>>>(dstp, deg);
  int nb = (NN + 1023) / 1024;
  k_scanA<<<nb, 1024, 0, stream>>>(deg, incl, bsum);
  k_scanB<<<1, 64, 0, stream>>>(bsum, nb);
  k_scanC<<<nb, 1024, 0, stream>>>(deg, incl, bsum, row_start, cursor);
  k_scatter<<<(EE + 255) / 256, 256, 0, stream>>>(srcp, dstp, cursor, csr_src);
  k_agg<<<NN, 256, 0, stream>>>(hb, a_src, a_dst, row_start, csr_src, bias, out);
}

// Round 2
// 334.079 us; speedup vs baseline: 1.3404x; 1.3404x over previous
//
#include <hip/hip_runtime.h>
#include <hip/hip_bf16.h>

#define NN 50000
#define EE 200000
#define HH 8
#define CC 256
#define IND 256
#define HC 2048
#define NEG 0.2f
#define EPSV 1e-16f

typedef __attribute__((ext_vector_type(8))) short short8;
typedef __attribute__((ext_vector_type(4))) float f32x4;

__device__ __forceinline__ float b2f(unsigned short u) {
  return __uint_as_float(((unsigned)u) << 16);
}
__device__ __forceinline__ unsigned short f2b(float f) {
  unsigned u = __float_as_uint(f);
  unsigned r = (u + 0x7FFFu + ((u >> 16) & 1u)) >> 16;
  return (unsigned short)r;
}

// ---------------- convert x to bf16 ----------------
__global__ __launch_bounds__(256) void k_convert(const float* __restrict__ x,
                                                 unsigned short* __restrict__ xb) {
  int i = blockIdx.x * 256 + threadIdx.x;
  const int NX4 = NN * IND / 4;
  if (i < NX4) {
    float4 v = ((const float4*)x)[i];
    ushort4 o = make_ushort4(f2b(v.x), f2b(v.y), f2b(v.z), f2b(v.w));
    ((ushort4*)xb)[i] = o;
  }
}

// ---------------- transpose W [256][2048] f32 -> wt [2048][256] bf16 ----------------
__global__ __launch_bounds__(1024) void k_trans(const float* __restrict__ W,
                                                unsigned short* __restrict__ wt) {
  __shared__ float tile[32][33];
  int cx = blockIdx.x * 32;   // over HC
  int kx = blockIdx.y * 32;   // over IND
  int tx = threadIdx.x & 31, ty = threadIdx.x >> 5;
  tile[ty][tx] = W[(size_t)(kx + ty) * HC + cx + tx];
  __syncthreads();
  wt[(size_t)(cx + ty) * IND + kx + tx] = f2b(tile[tx][ty]);
}

// ---------------- fold W against att vectors: wfold[in][h] ----------------
__global__ __launch_bounds__(256) void k_wfold(const float* __restrict__ W,
                                               const float* __restrict__ att_s,
                                               const float* __restrict__ att_d,
                                               float* __restrict__ wsrc,
                                               float* __restrict__ wdst) {
  int in = blockIdx.x;
  int t = threadIdx.x;
  int h = t >> 5;
  int c0 = (t & 31) * 8;
  float ps = 0.f, pd = 0.f;
#pragma unroll
  for (int j = 0; j < 8; ++j) {
    float wv = W[(size_t)in * HC + h * 256 + c0 + j];
    ps += wv * att_s[h * 256 + c0 + j];
    pd += wv * att_d[h * 256 + c0 + j];
  }
#pragma unroll
  for (int o = 16; o >= 1; o >>= 1) {
    ps += __shfl_down(ps, o, 32);
    pd += __shfl_down(pd, o, 32);
  }
  if ((t & 31) == 0) {
    wsrc[in * HH + h] = ps;
    wdst[in * HH + h] = pd;
  }
}

// ---------------- per-node logits from x (f32): a = x @ wfold ----------------
__global__ __launch_bounds__(256) void k_alog2(const float* __restrict__ x,
                                               const float* __restrict__ wsrc,
                                               const float* __restrict__ wdst,
                                               float* __restrict__ a_src,
                                               float* __restrict__ a_dst) {
  const int l = threadIdx.x & 63;
  const int gwave = (blockIdx.x * 256 + threadIdx.x) >> 6;
  const int nwaves = (gridDim.x * 256) >> 6;
  // register-resident wfold slices for this lane's 4 input dims
  float ws_[4][8], wd_[4][8];
#pragma unroll
  for (int j = 0; j < 4; ++j) {
#pragma unroll
    for (int h = 0; h < 8; ++h) {
      ws_[j][h] = wsrc[(l * 4 + j) * HH + h];
      wd_[j][h] = wdst[(l * 4 + j) * HH + h];
    }
  }
  for (int n = gwave; n < NN; n += nwaves) {
    float4 xv = *(const float4*)(x + (size_t)n * IND + l * 4);
    float xa[4] = {xv.x, xv.y, xv.z, xv.w};
    float as[8] = {}, ad[8] = {};
#pragma unroll
    for (int j = 0; j < 4; ++j)
#pragma unroll
      for (int h = 0; h < 8; ++h) {
        as[h] += xa[j] * ws_[j][h];
        ad[h] += xa[j] * wd_[j][h];
      }
#pragma unroll
    for (int o = 32; o >= 1; o >>= 1) {
#pragma unroll
      for (int h = 0; h < 8; ++h) {
        as[h] += __shfl_down(as[h], o);
        ad[h] += __shfl_down(ad[h], o);
      }
    }
    if (l == 0) {
#pragma unroll
      for (int h = 0; h < 8; ++h) {
        a_src[n * HH + h] = as[h];
        a_dst[n * HH + h] = ad[h];
      }
    }
  }
}

// ---------------- GEMM: h = x @ W (bf16 MFMA, 128x128 tile, BK=64) ----------------
// LDS layout: A[128][64] bf16 (row stride 128B, 8 chunks of 16B), XOR-swizzled:
// chunk' = chunk ^ (row&7). Staged via global_load_lds (linear LDS dest,
// inverse-swizzled per-lane global source), read with swizzled ds_read_b128.
__global__ __launch_bounds__(256) void k_gemm(const unsigned short* __restrict__ xb,
                                              const unsigned short* __restrict__ wt,
                                              unsigned short* __restrict__ hb) {
  __shared__ unsigned short As[128 * 64];
  __shared__ unsigned short Bs[128 * 64];
  const int t = threadIdx.x;
  const int lane = t & 63;
  const int w = t >> 6;
  const int wr = w >> 1, wc = w & 1;
  const int l16 = lane & 15;
  const int lq = lane >> 4;          // 0..3
  const int m0 = blockIdx.y * 128;
  const int n0 = blockIdx.x * 128;

  f32x4 acc[4][4] = {};

  // precompute staging row/chunk for this thread (same for A and B)
  const int so = w * 1024 + lane * 16;      // byte offset within a 4KB issue-slice
  for (int ks = 0; ks < 4; ++ks) {
    const int k0 = ks * 64;
#pragma unroll
    for (int i = 0; i < 4; ++i) {
      int o = i * 4096 + so;                // linear LDS byte offset
      int row = o >> 7;                     // 128B per row
      int chunk = (o >> 4) & 7;
      int cg = chunk ^ (row & 7);           // inverse swizzle on global source
      const unsigned short* srcA = xb + (size_t)(m0 + row) * IND + k0 + cg * 8;
      const unsigned short* srcB = wt + (size_t)(n0 + row) * IND + k0 + cg * 8;
      __builtin_amdgcn_global_load_lds(
          (const __attribute__((address_space(1))) void*)srcA,
          (__attribute__((address_space(3))) void*)((char*)As + i * 4096 + w * 1024),
          16, 0, 0);
      __builtin_amdgcn_global_load_lds(
          (const __attribute__((address_space(1))) void*)srcB,
          (__attribute__((address_space(3))) void*)((char*)Bs + i * 4096 + w * 1024),
          16, 0, 0);
    }
    __syncthreads();
#pragma unroll
    for (int kk = 0; kk < 2; ++kk) {
      short8 af[4], bf[4];
#pragma unroll
      for (int m = 0; m < 4; ++m) {
        int row = wr * 64 + m * 16 + l16;
        int byte = row * 128 + (((kk * 4 + lq) ^ (row & 7)) << 4);
        af[m] = *(const short8*)((const char*)As + byte);
      }
#pragma unroll
      for (int n = 0; n < 4; ++n) {
        int row = wc * 64 + n * 16 + l16;
        int byte = row * 128 + (((kk * 4 + lq) ^ (row & 7)) << 4);
        bf[n] = *(const short8*)((const char*)Bs + byte);
      }
#pragma unroll
      for (int m = 0; m < 4; ++m)
#pragma unroll
        for (int n = 0; n < 4; ++n)
          acc[m][n] = __builtin_amdgcn_mfma_f32_16x16x32_bf16(af[m], bf[n], acc[m][n], 0, 0, 0);
    }
    __syncthreads();
  }

  const int r0 = lq * 4;
#pragma unroll
  for (int m = 0; m < 4; ++m) {
#pragma unroll
    for (int r = 0; r < 4; ++r) {
      int grow = m0 + wr * 64 + m * 16 + r0 + r;
      if (grow >= NN) continue;
#pragma unroll
      for (int n = 0; n < 4; ++n) {
        int gcol = n0 + wc * 64 + n * 16 + l16;
        hb[(size_t)grow * HC + gcol] = f2b(acc[m][n][r]);
      }
    }
  }
}

// ---------------- CSR build ----------------
__global__ void k_hist(const int* __restrict__ dstn, int* __restrict__ deg) {
  int e = blockIdx.x * 256 + threadIdx.x;
  if (e < EE) atomicAdd(&deg[dstn[e]], 1);
}

__global__ __launch_bounds__(1024) void k_scanA(const int* __restrict__ deg,
                                                int* __restrict__ incl, int* __restrict__ bsum) {
  __shared__ int s[1024];
  int tid = threadIdx.x;
  int i = blockIdx.x * 1024 + tid;
  s[tid] = (i < NN) ? deg[i] : 0;
  __syncthreads();
  for (int o = 1; o < 1024; o <<= 1) {
    int add = (tid >= o) ? s[tid - o] : 0;
    __syncthreads();
    s[tid] += add;
    __syncthreads();
  }
  if (i < NN) incl[i] = s[tid];
  if (tid == 1023) bsum[blockIdx.x] = s[1023];
}

__global__ void k_scanB(int* bsum, int nb) {
  if (threadIdx.x == 0 && blockIdx.x == 0) {
    int run = 0;
    for (int b = 0; b < nb; ++b) { int v = bsum[b]; bsum[b] = run; run += v; }
  }
}

__global__ __launch_bounds__(1024) void k_scanC(const int* __restrict__ deg, const int* __restrict__ incl,
                                                const int* __restrict__ bsum, int* __restrict__ row_start,
                                                int* __restrict__ cursor) {
  int i = blockIdx.x * 1024 + threadIdx.x;
  if (i < NN) {
    int ex = bsum[i >> 10] + incl[i] - deg[i];
    row_start[i] = ex;
    cursor[i] = ex;
  }
  if (i == 0) row_start[NN] = EE;
}

__global__ void k_scatter(const int* __restrict__ srcn, const int* __restrict__ dstn,
                          int* __restrict__ cursor, int* __restrict__ csr_src) {
  int e = blockIdx.x * 256 + threadIdx.x;
  if (e < EE) {
    int d = dstn[e];
    int p = atomicAdd(&cursor[d], 1);
    csr_src[p] = srcn[e];
  }
}

// ---------------- fused segment softmax + aggregation ----------------
__global__ __launch_bounds__(256) void k_agg(const unsigned short* __restrict__ hb,
                                             const float* __restrict__ a_src,
                                             const float* __restrict__ a_dst,
                                             const int* __restrict__ row_start,
                                             const int* __restrict__ csr_src,
                                             const float* __restrict__ bias,
                                             float* __restrict__ out) {
  __shared__ float m_s[8], d_s[8];
  __shared__ float alpha_s[8][8];   // [edge_in_chunk][head]
  __shared__ int src_s[8];
  __shared__ float redf[8][256];
  int n = blockIdx.x;
  int t = threadIdx.x;
  int start = row_start[n];
  int D = row_start[n + 1] - start;
  if (D == 0) {
    out[(size_t)n * CC + t] = bias[t];
    return;
  }
  // phase A: online softmax stats (wave 0; lane = e8*8 + h)
  if (t < 64) {
    int h = t & 7, e8 = t >> 3;
    float adst = a_dst[n * HH + h];
    float m = -INFINITY, ss = 0.f;
    for (int base = 0; base < D; base += 8) {
      int e = base + e8;
      float lg = -INFINITY;
      if (e < D) {
        int s = csr_src[start + e];
        float xv = a_src[s * HH + h] + adst;
        lg = (xv > 0.f) ? xv : NEG * xv;
      }
      if (lg > m) { ss *= __expf(m - lg); m = lg; }
      if (e < D) ss += __expf(lg - m);
    }
#pragma unroll
    for (int mask = 8; mask < 64; mask <<= 1) {
      float mo = __shfl_xor(m, mask);
      float so = __shfl_xor(ss, mask);
      float nm = fmaxf(m, mo);
      float s1 = (m == -INFINITY) ? 0.f : ss * __expf(m - nm);
      float s2 = (mo == -INFINITY) ? 0.f : so * __expf(mo - nm);
      m = nm; ss = s1 + s2;
    }
    if (e8 == 0) { m_s[h] = m; d_s[h] = ss; }
  }
  __syncthreads();

  // phase B: aggregate; thread covers head hA, channels c8..c8+7
  const int hA = t >> 5;
  const int c8 = (t & 31) * 8;
  float acc[8] = {0.f, 0.f, 0.f, 0.f, 0.f, 0.f, 0.f, 0.f};
  for (int base = 0; base < D; base += 8) {
    int nch = min(8, D - base);
    if (t < 64) {
      int h = t & 7, e8 = t >> 3;
      if (e8 < nch) {
        int s = csr_src[start + base + e8];
        if (h == 0) src_s[e8] = s;
        float xv = a_src[s * HH + h] + a_dst[n * HH + h];
        float lg = (xv > 0.f) ? xv : NEG * xv;
        alpha_s[e8][h] = __expf(lg - m_s[h]) / (d_s[h] + EPSV);
      }
    }
    __syncthreads();
    for (int e = 0; e < nch; ++e) {
      const unsigned short* hp = hb + (size_t)src_s[e] * HC + hA * 256 + c8;
      short8 v = *(const short8*)hp;
      float a = alpha_s[e][hA];
#pragma unroll
      for (int j = 0; j < 8; ++j) acc[j] += a * b2f((unsigned short)v[j]);
    }
    __syncthreads();
  }
  // head-mean reduction (vectorized LDS writes)
  *(f32x4*)&redf[hA][c8] = *(f32x4*)&acc[0];
  *(f32x4*)&redf[hA][c8 + 4] = *(f32x4*)&acc[4];
  __syncthreads();
  float s = 0.f;
#pragma unroll
  for (int h = 0; h < 8; ++h) s += redf[h][t];
  out[(size_t)n * CC + t] = s * 0.125f + bias[t];
}

// ---------------- launch ----------------
extern "C" void kernel_launch(void* const* d_in, const int* in_sizes, int n_in,
                              void* d_out, int out_size, void* d_ws, size_t ws_size,
                              hipStream_t stream) {
  (void)in_sizes; (void)n_in; (void)out_size; (void)ws_size;
  const float* x = (const float*)d_in[0];
  const int* ei = (const int*)d_in[1];
  const float* W = (const float*)d_in[2];
  const float* att_s = (const float*)d_in[3];
  const float* att_d = (const float*)d_in[4];
  const float* bias = (const float*)d_in[5];
  float* out = (float*)d_out;
  const int* srcp = ei;
  const int* dstp = ei + EE;

  char* ws = (char*)d_ws;
  size_t off = 0;
  auto alloc = [&](size_t bytes) {
    void* p = ws + off;
    off = (off + bytes + 255) & ~(size_t)255;
    return p;
  };
  unsigned short* hb = (unsigned short*)alloc((size_t)NN * HC * 2);
  unsigned short* xb = (unsigned short*)alloc((size_t)NN * IND * 2);
  unsigned short* wt = (unsigned short*)alloc((size_t)HC * IND * 2);   // also OOB pad for xb
  float* wsrc = (float*)alloc((size_t)IND * HH * 4);
  float* wdst = (float*)alloc((size_t)IND * HH * 4);
  float* a_src = (float*)alloc((size_t)NN * HH * 4);
  float* a_dst = (float*)alloc((size_t)NN * HH * 4);
  int* deg = (int*)alloc((size_t)NN * 4);
  int* incl = (int*)alloc((size_t)NN * 4);
  int* row_start = (int*)alloc((size_t)(NN + 1) * 4);
  int* cursor = (int*)alloc((size_t)NN * 4);
  int* csr_src = (int*)alloc((size_t)EE * 4);
  int* bsum = (int*)alloc(256);

  hipMemsetAsync(deg, 0, (size_t)NN * 4, stream);

  k_convert<<<(NN * IND / 4 + 255) / 256, 256, 0, stream>>>(x, xb);
  k_trans<<<dim3(HC / 32, IND / 32), 1024, 0, stream>>>(W, wt);
  k_wfold<<<IND, 256, 0, stream>>>(W, att_s, att_d, wsrc, wdst);
  k_alog2<<<832, 256, 0, stream>>>(x, wsrc, wdst, a_src, a_dst);
  k_gemm<<<dim3(16, 391), 256, 0, stream>>>(xb, wt, hb);
  k_hist<<<(EE + 255) / 256, 256, 0, stream>>>(dstp, deg);
  int nb = (NN + 1023) / 1024;
  k_scanA<<<nb, 1024, 0, stream>>>(deg, incl, bsum);
  k_scanB<<<1, 64, 0, stream>>>(bsum, nb);
  k_scanC<<<nb, 1024, 0, stream>>>(deg, incl, bsum, row_start, cursor);
  k_scatter<<<(EE + 255) / 256, 256, 0, stream>>>(srcp, dstp, cursor, csr_src);
  k_agg<<<NN, 256, 0, stream>>>(hb, a_src, a_dst, row_start, csr_src, bias, out);
}

// Round 3
// 329.093 us; speedup vs baseline: 1.3607x; 1.0152x over previous
//
#include <hip/hip_runtime.h>
#include <hip/hip_bf16.h>

#define NN 50000
#define EE 200000
#define HH 8
#define CC 256
#define IND 256
#define HC 2048
#define NEG 0.2f
#define EPSV 1e-16f

typedef __attribute__((ext_vector_type(8))) short short8;
typedef __attribute__((ext_vector_type(4))) float f32x4;

__device__ __forceinline__ float b2f(unsigned short u) {
  return __uint_as_float(((unsigned)u) << 16);
}
__device__ __forceinline__ unsigned short f2b(float f) {
  unsigned u = __float_as_uint(f);
  unsigned r = (u + 0x7FFFu + ((u >> 16) & 1u)) >> 16;
  return (unsigned short)r;
}

// ---------------- convert x to bf16 ----------------
__global__ __launch_bounds__(256) void k_convert(const float* __restrict__ x,
                                                 unsigned short* __restrict__ xb) {
  int i = blockIdx.x * 256 + threadIdx.x;
  const int NX4 = NN * IND / 4;
  if (i < NX4) {
    float4 v = ((const float4*)x)[i];
    ushort4 o = make_ushort4(f2b(v.x), f2b(v.y), f2b(v.z), f2b(v.w));
    ((ushort4*)xb)[i] = o;
  }
}

// ---------------- transpose W [256][2048] f32 -> wt [2048][256] bf16 ----------------
__global__ __launch_bounds__(1024) void k_trans(const float* __restrict__ W,
                                                unsigned short* __restrict__ wt) {
  __shared__ float tile[32][33];
  int cx = blockIdx.x * 32;   // over HC
  int kx = blockIdx.y * 32;   // over IND
  int tx = threadIdx.x & 31, ty = threadIdx.x >> 5;
  tile[ty][tx] = W[(size_t)(kx + ty) * HC + cx + tx];
  __syncthreads();
  wt[(size_t)(cx + ty) * IND + kx + tx] = f2b(tile[tx][ty]);
}

// ---------------- fold W against att vectors: wfold[in][h] ----------------
__global__ __launch_bounds__(256) void k_wfold(const float* __restrict__ W,
                                               const float* __restrict__ att_s,
                                               const float* __restrict__ att_d,
                                               float* __restrict__ wsrc,
                                               float* __restrict__ wdst) {
  int in = blockIdx.x;
  int t = threadIdx.x;
  int h = t >> 5;
  int c0 = (t & 31) * 8;
  float ps = 0.f, pd = 0.f;
#pragma unroll
  for (int j = 0; j < 8; ++j) {
    float wv = W[(size_t)in * HC + h * 256 + c0 + j];
    ps += wv * att_s[h * 256 + c0 + j];
    pd += wv * att_d[h * 256 + c0 + j];
  }
#pragma unroll
  for (int o = 16; o >= 1; o >>= 1) {
    ps += __shfl_down(ps, o, 32);
    pd += __shfl_down(pd, o, 32);
  }
  if ((t & 31) == 0) {
    wsrc[in * HH + h] = ps;
    wdst[in * HH + h] = pd;
  }
}

// ---------------- per-node logits from x (f32): a = x @ wfold ----------------
__global__ __launch_bounds__(256) void k_alog2(const float* __restrict__ x,
                                               const float* __restrict__ wsrc,
                                               const float* __restrict__ wdst,
                                               float* __restrict__ a_src,
                                               float* __restrict__ a_dst) {
  const int l = threadIdx.x & 63;
  const int gwave = (blockIdx.x * 256 + threadIdx.x) >> 6;
  const int nwaves = (gridDim.x * 256) >> 6;
  float ws_[4][8], wd_[4][8];
#pragma unroll
  for (int j = 0; j < 4; ++j) {
#pragma unroll
    for (int h = 0; h < 8; ++h) {
      ws_[j][h] = wsrc[(l * 4 + j) * HH + h];
      wd_[j][h] = wdst[(l * 4 + j) * HH + h];
    }
  }
  for (int n = gwave; n < NN; n += nwaves) {
    float4 xv = *(const float4*)(x + (size_t)n * IND + l * 4);
    float xa[4] = {xv.x, xv.y, xv.z, xv.w};
    float as[8] = {}, ad[8] = {};
#pragma unroll
    for (int j = 0; j < 4; ++j)
#pragma unroll
      for (int h = 0; h < 8; ++h) {
        as[h] += xa[j] * ws_[j][h];
        ad[h] += xa[j] * wd_[j][h];
      }
#pragma unroll
    for (int o = 32; o >= 1; o >>= 1) {
#pragma unroll
      for (int h = 0; h < 8; ++h) {
        as[h] += __shfl_down(as[h], o);
        ad[h] += __shfl_down(ad[h], o);
      }
    }
    if (l == 0) {
#pragma unroll
      for (int h = 0; h < 8; ++h) {
        a_src[n * HH + h] = as[h];
        a_dst[n * HH + h] = ad[h];
      }
    }
  }
}

// ---------------- GEMM: h = x @ W (bf16 MFMA, 128x128 tile, BK=64) ----------------
__global__ __launch_bounds__(256) void k_gemm(const unsigned short* __restrict__ xb,
                                              const unsigned short* __restrict__ wt,
                                              unsigned short* __restrict__ hb) {
  __shared__ unsigned short As[128 * 64];
  __shared__ unsigned short Bs[128 * 64];
  const int t = threadIdx.x;
  const int lane = t & 63;
  const int w = t >> 6;
  const int wr = w >> 1, wc = w & 1;
  const int l16 = lane & 15;
  const int lq = lane >> 4;          // 0..3
  const int m0 = blockIdx.y * 128;
  const int n0 = blockIdx.x * 128;

  f32x4 acc[4][4] = {};

  const int so = w * 1024 + lane * 16;      // byte offset within a 4KB issue-slice
  for (int ks = 0; ks < 4; ++ks) {
    const int k0 = ks * 64;
#pragma unroll
    for (int i = 0; i < 4; ++i) {
      int o = i * 4096 + so;                // linear LDS byte offset
      int row = o >> 7;                     // 128B per row
      int chunk = (o >> 4) & 7;
      int cg = chunk ^ (row & 7);           // inverse swizzle on global source
      const unsigned short* srcA = xb + (size_t)(m0 + row) * IND + k0 + cg * 8;
      const unsigned short* srcB = wt + (size_t)(n0 + row) * IND + k0 + cg * 8;
      __builtin_amdgcn_global_load_lds(
          (const __attribute__((address_space(1))) void*)srcA,
          (__attribute__((address_space(3))) void*)((char*)As + i * 4096 + w * 1024),
          16, 0, 0);
      __builtin_amdgcn_global_load_lds(
          (const __attribute__((address_space(1))) void*)srcB,
          (__attribute__((address_space(3))) void*)((char*)Bs + i * 4096 + w * 1024),
          16, 0, 0);
    }
    __syncthreads();
#pragma unroll
    for (int kk = 0; kk < 2; ++kk) {
      short8 af[4], bf[4];
#pragma unroll
      for (int m = 0; m < 4; ++m) {
        int row = wr * 64 + m * 16 + l16;
        int byte = row * 128 + (((kk * 4 + lq) ^ (row & 7)) << 4);
        af[m] = *(const short8*)((const char*)As + byte);
      }
#pragma unroll
      for (int n = 0; n < 4; ++n) {
        int row = wc * 64 + n * 16 + l16;
        int byte = row * 128 + (((kk * 4 + lq) ^ (row & 7)) << 4);
        bf[n] = *(const short8*)((const char*)Bs + byte);
      }
#pragma unroll
      for (int m = 0; m < 4; ++m)
#pragma unroll
        for (int n = 0; n < 4; ++n)
          acc[m][n] = __builtin_amdgcn_mfma_f32_16x16x32_bf16(af[m], bf[n], acc[m][n], 0, 0, 0);
    }
    __syncthreads();
  }

  const int r0 = lq * 4;
#pragma unroll
  for (int m = 0; m < 4; ++m) {
#pragma unroll
    for (int r = 0; r < 4; ++r) {
      int grow = m0 + wr * 64 + m * 16 + r0 + r;
      if (grow >= NN) continue;
#pragma unroll
      for (int n = 0; n < 4; ++n) {
        int gcol = n0 + wc * 64 + n * 16 + l16;
        hb[(size_t)grow * HC + gcol] = f2b(acc[m][n][r]);
      }
    }
  }
}

// ---------------- CSR build ----------------
__global__ void k_hist(const int* __restrict__ dstn, int* __restrict__ deg) {
  int e = blockIdx.x * 256 + threadIdx.x;
  if (e < EE) atomicAdd(&deg[dstn[e]], 1);
}

__global__ __launch_bounds__(1024) void k_scanA(const int* __restrict__ deg,
                                                int* __restrict__ incl, int* __restrict__ bsum) {
  __shared__ int s[1024];
  int tid = threadIdx.x;
  int i = blockIdx.x * 1024 + tid;
  s[tid] = (i < NN) ? deg[i] : 0;
  __syncthreads();
  for (int o = 1; o < 1024; o <<= 1) {
    int add = (tid >= o) ? s[tid - o] : 0;
    __syncthreads();
    s[tid] += add;
    __syncthreads();
  }
  if (i < NN) incl[i] = s[tid];
  if (tid == 1023) bsum[blockIdx.x] = s[1023];
}

__global__ void k_scanB(int* bsum, int nb) {
  if (threadIdx.x == 0 && blockIdx.x == 0) {
    int run = 0;
    for (int b = 0; b < nb; ++b) { int v = bsum[b]; bsum[b] = run; run += v; }
  }
}

__global__ __launch_bounds__(1024) void k_scanC(const int* __restrict__ deg, const int* __restrict__ incl,
                                                const int* __restrict__ bsum, int* __restrict__ row_start,
                                                int* __restrict__ cursor) {
  int i = blockIdx.x * 1024 + threadIdx.x;
  if (i < NN) {
    int ex = bsum[i >> 10] + incl[i] - deg[i];
    row_start[i] = ex;
    cursor[i] = ex;
  }
  if (i == 0) row_start[NN] = EE;
}

__global__ void k_scatter(const int* __restrict__ srcn, const int* __restrict__ dstn,
                          int* __restrict__ cursor, int* __restrict__ csr_src) {
  int e = blockIdx.x * 256 + threadIdx.x;
  if (e < EE) {
    int d = dstn[e];
    int p = atomicAdd(&cursor[d], 1);
    csr_src[p] = srcn[e];
  }
}

// ---------------- fused segment softmax + aggregation: ONE NODE PER WAVE ----------------
// lane layout: softmax phase (e8 = l>>3, h = l&7); agg phase lane owns channels l*4..l*4+3
// No LDS, no __syncthreads. Head-mean folds into per-lane accumulation.
__global__ __launch_bounds__(256) void k_agg(const unsigned short* __restrict__ hb,
                                             const float* __restrict__ a_src,
                                             const float* __restrict__ a_dst,
                                             const int* __restrict__ row_start,
                                             const int* __restrict__ csr_src,
                                             const float* __restrict__ bias,
                                             float* __restrict__ out) {
  const int l = threadIdx.x & 63;
  const int n = blockIdx.x * 4 + (threadIdx.x >> 6);
  if (n >= NN) return;
  const int h = l & 7;
  const int e8 = l >> 3;
  const int start = row_start[n];
  const int D = row_start[n + 1] - start;
  float4 bv = *(const float4*)(bias + l * 4);
  float* op = out + (size_t)n * CC + l * 4;
  if (D == 0) {
    *(float4*)op = bv;
    return;
  }
  const float adst = a_dst[n * HH + h];

  // ---- softmax stats, chunk 0 (keep lg0/s0 for reuse in agg) ----
  int s0 = 0;
  float lg0 = -INFINITY;
  if (e8 < D) {
    s0 = csr_src[start + e8];
    float xv = a_src[s0 * HH + h] + adst;
    lg0 = (xv > 0.f) ? xv : NEG * xv;
  }
  float m = lg0;
  float ss = (e8 < D) ? 1.f : 0.f;
  for (int base = 8; base < D; base += 8) {
    int e = base + e8;
    float lg = -INFINITY;
    if (e < D) {
      int s = csr_src[start + e];
      float xv = a_src[s * HH + h] + adst;
      lg = (xv > 0.f) ? xv : NEG * xv;
    }
    if (lg > m) { ss *= __expf(m - lg); m = lg; }
    if (e < D) ss += __expf(lg - m);
  }
  // combine across the 8 e8-groups (per-head stats end up in every lane of that h)
#pragma unroll
  for (int mask = 8; mask < 64; mask <<= 1) {
    float mo = __shfl_xor(m, mask, 64);
    float so = __shfl_xor(ss, mask, 64);
    float nm = fmaxf(m, mo);
    float s1 = (m == -INFINITY) ? 0.f : ss * __expf(m - nm);
    float s2 = (mo == -INFINITY) ? 0.f : so * __expf(mo - nm);
    m = nm;
    ss = s1 + s2;
  }
  const float inv = 1.f / (ss + EPSV);

  // ---- aggregation: lane covers channels l*4..l*4+3, loops all 8 heads ----
  float acc0 = 0.f, acc1 = 0.f, acc2 = 0.f, acc3 = 0.f;
  const unsigned short* hbase = hb + (size_t)l * 4;
  for (int base = 0; base < D; base += 8) {
    int nch = min(8, D - base);
    int s;
    float lg;
    if (base == 0) {
      s = s0;
      lg = lg0;
    } else {
      int e = base + e8;
      s = 0;
      lg = -INFINITY;
      if (e < D) {
        s = csr_src[start + e];
        float xv = a_src[s * HH + h] + adst;
        lg = (xv > 0.f) ? xv : NEG * xv;
      }
    }
    float alpha = __expf(lg - m) * inv;   // 0 for lanes past D
    for (int e = 0; e < nch; ++e) {
      int se = __shfl(s, e * 8, 64);
      const unsigned short* hp = hbase + (size_t)se * HC;
#pragma unroll
      for (int hh = 0; hh < 8; ++hh) {
        float ah = __shfl(alpha, e * 8 + hh, 64);
        ushort4 v = *(const ushort4*)(hp + hh * 256);
        acc0 += ah * b2f(v.x);
        acc1 += ah * b2f(v.y);
        acc2 += ah * b2f(v.z);
        acc3 += ah * b2f(v.w);
      }
    }
  }
  *(float4*)op = make_float4(acc0 * 0.125f + bv.x, acc1 * 0.125f + bv.y,
                             acc2 * 0.125f + bv.z, acc3 * 0.125f + bv.w);
}

// ---------------- launch ----------------
extern "C" void kernel_launch(void* const* d_in, const int* in_sizes, int n_in,
                              void* d_out, int out_size, void* d_ws, size_t ws_size,
                              hipStream_t stream) {
  (void)in_sizes; (void)n_in; (void)out_size; (void)ws_size;
  const float* x = (const float*)d_in[0];
  const int* ei = (const int*)d_in[1];
  const float* W = (const float*)d_in[2];
  const float* att_s = (const float*)d_in[3];
  const float* att_d = (const float*)d_in[4];
  const float* bias = (const float*)d_in[5];
  float* out = (float*)d_out;
  const int* srcp = ei;
  const int* dstp = ei + EE;

  char* ws = (char*)d_ws;
  size_t off = 0;
  auto alloc = [&](size_t bytes) {
    void* p = ws + off;
    off = (off + bytes + 255) & ~(size_t)255;
    return p;
  };
  unsigned short* hb = (unsigned short*)alloc((size_t)NN * HC * 2);
  unsigned short* xb = (unsigned short*)alloc((size_t)NN * IND * 2);
  unsigned short* wt = (unsigned short*)alloc((size_t)HC * IND * 2);   // also OOB pad for xb
  float* wsrc = (float*)alloc((size_t)IND * HH * 4);
  float* wdst = (float*)alloc((size_t)IND * HH * 4);
  float* a_src = (float*)alloc((size_t)NN * HH * 4);
  float* a_dst = (float*)alloc((size_t)NN * HH * 4);
  int* deg = (int*)alloc((size_t)NN * 4);
  int* incl = (int*)alloc((size_t)NN * 4);
  int* row_start = (int*)alloc((size_t)(NN + 1) * 4);
  int* cursor = (int*)alloc((size_t)NN * 4);
  int* csr_src = (int*)alloc((size_t)EE * 4);
  int* bsum = (int*)alloc(256);

  hipMemsetAsync(deg, 0, (size_t)NN * 4, stream);

  k_convert<<<(NN * IND / 4 + 255) / 256, 256, 0, stream>>>(x, xb);
  k_trans<<<dim3(HC / 32, IND / 32), 1024, 0, stream>>>(W, wt);
  k_wfold<<<IND, 256, 0, stream>>>(W, att_s, att_d, wsrc, wdst);
  k_alog2<<<832, 256, 0, stream>>>(x, wsrc, wdst, a_src, a_dst);
  k_gemm<<<dim3(16, 391), 256, 0, stream>>>(xb, wt, hb);
  k_hist<<<(EE + 255) / 256, 256, 0, stream>>>(dstp, deg);
  int nb = (NN + 1023) / 1024;
  k_scanA<<<nb, 1024, 0, stream>>>(deg, incl, bsum);
  k_scanB<<<1, 64, 0, stream>>>(bsum, nb);
  k_scanC<<<nb, 1024, 0, stream>>>(deg, incl, bsum, row_start, cursor);
  k_scatter<<<(EE + 255) / 256, 256, 0, stream>>>(srcp, dstp, cursor, csr_src);
  k_agg<<<(NN + 3) / 4, 256, 0, stream>>>(hb, a_src, a_dst, row_start, csr_src, bias, out);
}